// Round 6
// baseline (167.429 us; speedup 1.0000x reference)
//
#include <hip/hip_runtime.h>

constexpr int B = 512;
constexpr int D = 2048;
constexpr int C = 10000;
constexpr long long ND = (long long)C * D;      // 20,480,000
constexpr int BMW = (C + 31) / 32;              // 313 bitmap words
constexpr int NBLK = 2048;                      // all blocks copy; first B also group

typedef float vfloat4 __attribute__((ext_vector_type(4)));  // native vec for NT store

// ---------------------------------------------------------------------------
// K0 (tiny): zero the loss slot, build touched-row bitmap in ws.
// ---------------------------------------------------------------------------
__global__ void prep_kernel(const int* __restrict__ labels,
                            float* __restrict__ out,
                            unsigned int* __restrict__ bitmap) {
    __shared__ unsigned int sb[BMW];
    const int tx = threadIdx.x;
    for (int j = tx; j < BMW; j += blockDim.x) sb[j] = 0u;
    __syncthreads();
    int l = labels[tx];
    atomicOr(&sb[l >> 5], 1u << (l & 31));
    __syncthreads();
    for (int j = tx; j < BMW; j += blockDim.x) bitmap[j] = sb[j];
    if (tx == 0) out[0] = 0.0f;
}

// ---------------------------------------------------------------------------
// K1 (fused): blocks [0,B) first do the group role (closed-form EMA update of
// touched rows + loss), then ALL blocks run the copy role over untouched rows.
// Copy loop is 4x-batched: 4 independent float4 loads in flight per thread
// (the R4 version had 1 -> latency-serialized at 2.4 TB/s).
// ---------------------------------------------------------------------------
__global__ __launch_bounds__(256) void fused_kernel(
        const float* __restrict__ features,
        const int* __restrict__ labels,
        const float* __restrict__ centers,
        const unsigned int* __restrict__ bitmap,
        float* __restrict__ out) {
    __shared__ int sl[B];
    __shared__ int mem[B];
    __shared__ unsigned int sb[BMW];
    __shared__ float wsum[4];
    const int tx  = threadIdx.x;
    const int bid = blockIdx.x;

    for (int j = tx; j < BMW; j += 256) sb[j] = bitmap[j];
    if (bid < B) {
        for (int j = tx; j < B; j += 256) sl[j] = labels[j];
    }
    __syncthreads();

    if (bid < B) {
        // ----------------- group role: one block per sample -----------------
        const int i = bid;
        const int l = sl[i];
        int k = 0;
        bool rank0 = true;                       // block-uniform
        for (int j = 0; j < B; ++j) {
            if (sl[j] == l) {
                if (j < i) { rank0 = false; break; }
                mem[k++] = j;                    // uniform write, benign race
            }
        }
        if (rank0) {
            const float kc = exp2f(-(float)k);   // 0.5^k
            const float* __restrict__ crow = centers + (long long)l * D;
            float*       __restrict__ orow = out + 1 + (long long)l * D;
            float cv[8], acc[8];
            float lsum = 0.0f;
#pragma unroll
            for (int jj = 0; jj < 8; ++jj) {
                cv[jj]  = crow[tx + jj * 256];
                acc[jj] = kc * cv[jj];
            }
            for (int r = 0; r < k; ++r) {
                const float* __restrict__ frow = features + (long long)mem[r] * D;
                const float coef = exp2f(-(float)(k - r));   // 0.5^(k-r)
#pragma unroll
                for (int jj = 0; jj < 8; ++jj) {
                    float fv = frow[tx + jj * 256];
                    float d  = fv - cv[jj];
                    lsum    += d * d;
                    acc[jj] += coef * fv;
                }
            }
#pragma unroll
            for (int jj = 0; jj < 8; ++jj) orow[tx + jj * 256] = acc[jj];

            for (int off = 32; off > 0; off >>= 1) lsum += __shfl_down(lsum, off);
            if ((tx & 63) == 0) wsum[tx >> 6] = lsum;
            __syncthreads();                     // block-uniform (rank0 uniform)
            if (tx == 0) {
                float tot = wsum[0] + wsum[1] + wsum[2] + wsum[3];
                atomicAdd(out, tot * (1.0f / ((float)B * (float)D)));
            }
        }
    }

    // ----------------- copy role: all blocks, 4x-batched ---------------------
    const long long M = ND / 4;                  // 5,120,000 float4s
    const long long stride = (long long)NBLK * 256;
    const int lane = tx & 63;
    const float4* __restrict__ src = reinterpret_cast<const float4*>(centers);
    vfloat4*      __restrict__ dst = reinterpret_cast<vfloat4*>(out);

    auto store_one = [&](long long m, float4 v, float pw) {
        // out[4m] <- centers[4m-1] (row r0); out[4m+1..3] <- centers[4m..4m+2] (row r1)
        int r1 = (int)((4 * m) >> 11);
        bool t1 = (sb[r1 >> 5] >> (r1 & 31)) & 1u;
        bool t0;
        if (m == 0) {
            t0 = true;                           // out[0] is the loss slot
        } else {
            int r0 = (int)((4 * m - 1) >> 11);
            t0 = (sb[r0 >> 5] >> (r0 & 31)) & 1u;
        }
        if (!t0 && !t1) {
            vfloat4 w; w.x = pw; w.y = v.x; w.z = v.y; w.w = v.z;
            __builtin_nontemporal_store(w, &dst[m]);
        } else if (!t0) {
            out[4 * m] = pw;
        } else if (!t1) {
            out[4 * m + 1] = v.x;
            out[4 * m + 2] = v.y;
            out[4 * m + 3] = v.z;
        }
    };

    long long t = (long long)bid * 256 + tx;
    long long m = t;
    for (; m + 3 * stride < M; m += 4 * stride) {
        long long m0 = m, m1 = m + stride, m2 = m + 2 * stride, m3 = m + 3 * stride;
        float4 v0 = src[m0];                     // 4 independent loads in flight
        float4 v1 = src[m1];
        float4 v2 = src[m2];
        float4 v3 = src[m3];
        float pw0 = __shfl_up(v0.w, 1);
        float pw1 = __shfl_up(v1.w, 1);
        float pw2 = __shfl_up(v2.w, 1);
        float pw3 = __shfl_up(v3.w, 1);
        if (lane == 0) {                         // patch loads, also independent
            pw0 = (m0 > 0) ? centers[4 * m0 - 1] : 0.0f;
            pw1 = centers[4 * m1 - 1];
            pw2 = centers[4 * m2 - 1];
            pw3 = centers[4 * m3 - 1];
        }
        store_one(m0, v0, pw0);
        store_one(m1, v1, pw1);
        store_one(m2, v2, pw2);
        store_one(m3, v3, pw3);
    }
    for (; m < M; m += stride) {
        float4 v = src[m];
        float pw = __shfl_up(v.w, 1);
        if (lane == 0 && m > 0) pw = centers[4 * m - 1];
        store_one(m, v, pw);
    }
    if (t == 0) {                                // final element out[ND]
        int r = C - 1;
        if (!((sb[r >> 5] >> (r & 31)) & 1u)) out[ND] = centers[ND - 1];
    }
}

extern "C" void kernel_launch(void* const* d_in, const int* in_sizes, int n_in,
                              void* d_out, int out_size, void* d_ws, size_t ws_size,
                              hipStream_t stream) {
    const float* features = (const float*)d_in[0];
    const int*   labels   = (const int*)d_in[1];
    const float* centers  = (const float*)d_in[2];
    float*       out      = (float*)d_out;
    unsigned int* bitmap  = (unsigned int*)d_ws;

    prep_kernel<<<1, B, 0, stream>>>(labels, out, bitmap);
    fused_kernel<<<NBLK, 256, 0, stream>>>(features, labels, centers,
                                           bitmap, out);
}